// Round 3
// baseline (794.939 us; speedup 1.0000x reference)
//
#include <hip/hip_runtime.h>

// LSTM: B=4096, T=512, I=2, H=50, O=3.
// Round 3: force true register residency of W_hh.
//  - amdgpu_waves_per_eu(2,2): plan for 2 waves/EU -> 256-VGPR budget
//    (grid only supplies 2 waves/SIMD anyway, so no occupancy loss).
//  - asm-pin each weight pair after load: blocks rematerialization/reload.
//  - split accumulators (even/odd) to halve serial FMA chain depth.
// lane = hidden unit (padded 50->64), wave = 2 batch rows, block = 4 waves,
// 512 blocks. No barriers anywhere (h rows are wave-private).

typedef float v2f __attribute__((ext_vector_type(2)));

#define T_STEPS 512
#define HID     50
#define NB      2
#define WAVES   4
#define BCHUNK  (WAVES*NB)   // 8 batch rows per block

__device__ __forceinline__ float fsig(float x) {
    float e = __builtin_amdgcn_exp2f(-1.442695040888963f * x);
    return __builtin_amdgcn_rcpf(1.0f + e);
}
__device__ __forceinline__ float ftanh(float x) {
    float e = __builtin_amdgcn_exp2f(2.885390081777927f * x);
    return 1.0f - 2.0f * __builtin_amdgcn_rcpf(e + 1.0f);
}

__global__ __launch_bounds__(256)
__attribute__((amdgpu_waves_per_eu(2, 2)))
void lstm_fused_kernel(
    const float* __restrict__ x,     // [B,T,2]
    const float* __restrict__ W_ih,  // [200,2]
    const float* __restrict__ W_hh,  // [200,50]
    const float* __restrict__ b_ih,  // [200]
    const float* __restrict__ b_hh,  // [200]
    const float* __restrict__ W_fc,  // [3,50]
    const float* __restrict__ b_fc,  // [3]
    float* __restrict__ out)         // [B,3]
{
    __shared__ float h_lds[BCHUNK * 64];   // [row][hk], wave-private rows

    const int tid  = threadIdx.x;
    const int hk   = tid & 63;
    const int tb   = tid >> 6;
    const bool real = (hk < HID);
    const int j    = real ? hk : 0;

    // ---- one-time load of recurrent weights into VGPRs ----
    // wif[k]=(Wi[hk][k],Wf[hk][k]), wgo[k]=(Wg[hk][k],Wo[hk][k])
    const float* Wi = W_hh + (size_t)(0 * HID + j) * HID;
    const float* Wf = W_hh + (size_t)(1 * HID + j) * HID;
    const float* Wg = W_hh + (size_t)(2 * HID + j) * HID;
    const float* Wo = W_hh + (size_t)(3 * HID + j) * HID;

    v2f wif[HID], wgo[HID];
#pragma unroll
    for (int k = 0; k < HID; ++k) {
        if (real) {
            wif[k] = (v2f){Wi[k], Wf[k]};
            wgo[k] = (v2f){Wg[k], Wo[k]};
        } else {
            wif[k] = (v2f){0.f, 0.f};
            wgo[k] = (v2f){0.f, 0.f};
        }
    }
    // Pin: make values opaque so the allocator cannot remat/reload them.
#pragma unroll
    for (int k = 0; k < HID; ++k) {
        asm volatile("" : "+v"(wif[k]), "+v"(wgo[k]));
    }

    // biases (b_ih + b_hh) and input weights, gate-paired
    v2f bif, bgo, xw0if, xw0go, xw1if, xw1go;
    {
        int ji = 0 * HID + j, jf = 1 * HID + j, jg = 2 * HID + j, jo = 3 * HID + j;
        bif   = (v2f){b_ih[ji] + b_hh[ji], b_ih[jf] + b_hh[jf]};
        bgo   = (v2f){b_ih[jg] + b_hh[jg], b_ih[jo] + b_hh[jo]};
        xw0if = (v2f){W_ih[ji * 2 + 0], W_ih[jf * 2 + 0]};
        xw1if = (v2f){W_ih[ji * 2 + 1], W_ih[jf * 2 + 1]};
        xw0go = (v2f){W_ih[jg * 2 + 0], W_ih[jo * 2 + 0]};
        xw1go = (v2f){W_ih[jg * 2 + 1], W_ih[jo * 2 + 1]};
    }

    const int b0 = blockIdx.x * BCHUNK + tb * NB;
    const float* xr0 = x + (size_t)b0 * (T_STEPS * 2);
    const float* xr1 = xr0 + T_STEPS * 2;

    const int hb0 = (tb * NB + 0) * 64;
    const int hb1 = (tb * NB + 1) * 64;

    h_lds[hb0 + hk] = 0.f;    // wave-private: no barrier needed
    h_lds[hb1 + hk] = 0.f;

    float c0 = 0.f, c1 = 0.f;

    float2 xc0 = *(const float2*)(xr0);
    float2 xc1 = *(const float2*)(xr1);

    for (int t = 0; t < T_STEPS; ++t) {
        int tn = (t + 1 < T_STEPS) ? (t + 1) : t;
        float2 xn0 = *(const float2*)(xr0 + tn * 2);
        float2 xn1 = *(const float2*)(xr1 + tn * 2);

        // split accumulators: a/b partials halve the serial chain depth
        v2f if0a = (v2f){0.f, 0.f}, if0b = (v2f){0.f, 0.f};
        v2f go0a = (v2f){0.f, 0.f}, go0b = (v2f){0.f, 0.f};
        v2f if1a = (v2f){0.f, 0.f}, if1b = (v2f){0.f, 0.f};
        v2f go1a = (v2f){0.f, 0.f}, go1b = (v2f){0.f, 0.f};

#pragma unroll
        for (int kk = 0; kk < 48; kk += 4) {
            float4 h0v = *(const float4*)&h_lds[hb0 + kk];
            float4 h1v = *(const float4*)&h_lds[hb1 + kk];
#pragma unroll
            for (int q = 0; q < 4; q += 2) {
                float h0 = (&h0v.x)[q], h0n = (&h0v.x)[q + 1];
                float h1 = (&h1v.x)[q], h1n = (&h1v.x)[q + 1];
                if0a += wif[kk + q] * (v2f){h0, h0};
                go0a += wgo[kk + q] * (v2f){h0, h0};
                if1a += wif[kk + q] * (v2f){h1, h1};
                go1a += wgo[kk + q] * (v2f){h1, h1};
                if0b += wif[kk + q + 1] * (v2f){h0n, h0n};
                go0b += wgo[kk + q + 1] * (v2f){h0n, h0n};
                if1b += wif[kk + q + 1] * (v2f){h1n, h1n};
                go1b += wgo[kk + q + 1] * (v2f){h1n, h1n};
            }
        }
        {   // tail k = 48, 49
            float2 h0v = *(const float2*)&h_lds[hb0 + 48];
            float2 h1v = *(const float2*)&h_lds[hb1 + 48];
            if0a += wif[48] * (v2f){h0v.x, h0v.x};
            go0a += wgo[48] * (v2f){h0v.x, h0v.x};
            if1a += wif[48] * (v2f){h1v.x, h1v.x};
            go1a += wgo[48] * (v2f){h1v.x, h1v.x};
            if0b += wif[49] * (v2f){h0v.y, h0v.y};
            go0b += wgo[49] * (v2f){h0v.y, h0v.y};
            if1b += wif[49] * (v2f){h1v.y, h1v.y};
            go1b += wgo[49] * (v2f){h1v.y, h1v.y};
        }

        v2f aif0 = bif + xw0if * (v2f){xc0.x, xc0.x} + xw1if * (v2f){xc0.y, xc0.y}
                 + (if0a + if0b);
        v2f ago0 = bgo + xw0go * (v2f){xc0.x, xc0.x} + xw1go * (v2f){xc0.y, xc0.y}
                 + (go0a + go0b);
        v2f aif1 = bif + xw0if * (v2f){xc1.x, xc1.x} + xw1if * (v2f){xc1.y, xc1.y}
                 + (if1a + if1b);
        v2f ago1 = bgo + xw0go * (v2f){xc1.x, xc1.x} + xw1go * (v2f){xc1.y, xc1.y}
                 + (go1a + go1b);

        // cell/hidden update, row 0
        {
            float ig = fsig(aif0.x), fg = fsig(aif0.y);
            float gg = ftanh(ago0.x), og = fsig(ago0.y);
            c0 = fg * c0 + ig * gg;
            h_lds[hb0 + hk] = og * ftanh(c0);
        }
        // row 1
        {
            float ig = fsig(aif1.x), fg = fsig(aif1.y);
            float gg = ftanh(ago1.x), og = fsig(ago1.y);
            c1 = fg * c1 + ig * gg;
            h_lds[hb1 + hk] = og * ftanh(c1);
        }
        xc0 = xn0; xc1 = xn1;
    }

    // ---- final FC: out[b][o] = h . W_fc[o] + b_fc[o] ----
    if (hk < 6) {
        int r = (hk >= 3) ? 1 : 0;
        int o = hk - r * 3;
        const int hb = (tb * NB + r) * 64;
        float s = b_fc[o];
        for (int k = 0; k < HID; ++k)
            s += h_lds[hb + k] * W_fc[o * HID + k];
        out[(size_t)(b0 + r) * 3 + o] = s;
    }
}

extern "C" void kernel_launch(void* const* d_in, const int* in_sizes, int n_in,
                              void* d_out, int out_size, void* d_ws, size_t ws_size,
                              hipStream_t stream) {
    const float* x    = (const float*)d_in[0];
    const float* W_ih = (const float*)d_in[1];
    const float* W_hh = (const float*)d_in[2];
    const float* b_ih = (const float*)d_in[3];
    const float* b_hh = (const float*)d_in[4];
    const float* W_fc = (const float*)d_in[5];
    const float* b_fc = (const float*)d_in[6];
    float* out = (float*)d_out;

    dim3 grid(4096 / BCHUNK);   // 512 blocks
    dim3 block(256);
    lstm_fused_kernel<<<grid, block, 0, stream>>>(x, W_ih, W_hh, b_ih, b_hh,
                                                  W_fc, b_fc, out);
}